// Round 3
// baseline (723.274 us; speedup 1.0000x reference)
//
#include <hip/hip_runtime.h>

// Entmax-1.5 loss, n=4096 rows x d=32000 fp32 logits -> scalar mean loss.
// Root-finding formulation (no sort): tau solves sum clip(x/2 - T, 0)^2 = 1,
// support always contained in {x > xmax - 2}.
//
// Round-3: split streaming from solving (r2 post-mortem: single-wave Newton
// tail per block blocked workgroup backfill -> ~300 us main kernel vs 83 us
// streaming roofline).
//  K1 entmax15_collect: per-row block; register-resident row (8x float4),
//     block max, ballot-compacted candidate push (x > xmax-2, store y=x/2)
//     into a per-row GLOBAL ws segment (CAPF=4096; overflow needs rowmax
//     < 3.13, P~7e-13; fallback solves from the raw row). All waves exit
//     together -> pure streaming.
//  K2 entmax15_solve: one wave per row; 12 Newton iters + exact quadratic
//     (reference formula) + loss terms from the ~450-candidate segment
//     (L2/L3-resident, 4096 concurrent waves).
//  K3 reduce_partials: sum per-row losses.
// Monolithic r2 kernel kept as fallback if ws is too small.

#define D          32000
#define NF4        8000      // D/4
#define REM4       832       // NF4 - 7*1024
#define BLK        1024
#define CAPF       4096      // per-row candidate capacity (floats)
#define NEWTON_IT  12

__device__ __forceinline__ int lane_prefix(unsigned long long b) {
    return __builtin_amdgcn_mbcnt_hi((unsigned int)(b >> 32),
           __builtin_amdgcn_mbcnt_lo((unsigned int)b, 0u));
}

// ---------------- K1: stream + max + compact to global ----------------
__global__ __launch_bounds__(BLK, 8)
void entmax15_collect(const float* __restrict__ x,
                      float* __restrict__ maxs,
                      int*   __restrict__ cnts,
                      float* __restrict__ cand) {
    __shared__ float s_red[16];
    __shared__ float s_max;
    __shared__ int   s_cnt;

    const int tid  = threadIdx.x;
    const int lane = tid & 63;
    const int wave = tid >> 6;
    const int r    = blockIdx.x;
    const float4* row4 = (const float4*)(x + (size_t)r * D);
    float* seg = cand + (size_t)r * CAPF;

    if (tid == 0) s_cnt = 0;

    float v[32];
#pragma unroll
    for (int i = 0; i < 7; ++i) {
        float4 t = row4[tid + i * 1024];
        v[4*i+0] = t.x; v[4*i+1] = t.y; v[4*i+2] = t.z; v[4*i+3] = t.w;
    }
    if (tid < REM4) {
        float4 t = row4[tid + 7 * 1024];
        v[28] = t.x; v[29] = t.y; v[30] = t.z; v[31] = t.w;
    } else {
        v[28] = v[29] = v[30] = v[31] = -1e30f;
    }

    // block max of x
    float m = -1e30f;
#pragma unroll
    for (int i = 0; i < 32; ++i) m = fmaxf(m, v[i]);
#pragma unroll
    for (int off = 32; off > 0; off >>= 1) m = fmaxf(m, __shfl_xor(m, off));
    if (lane == 0) s_red[wave] = m;
    __syncthreads();
    if (tid < 64) {
        float mm = (lane < 16) ? s_red[lane] : -1e30f;
#pragma unroll
        for (int off = 8; off > 0; off >>= 1) mm = fmaxf(mm, __shfl_xor(mm, off));
        if (lane == 0) s_max = mm;
    }
    __syncthreads();

    const float thr = s_max - 2.0f;   // exact: support subset of {x > xmax-2}

    // ballot-aggregated compaction: consecutive-address global writes
#pragma unroll
    for (int i = 0; i < 32; ++i) {
        bool cnd = (v[i] > thr);
        unsigned long long b = __ballot(cnd);
        if (b) {                               // wave-uniform branch
            int base = 0;
            if (lane == 0) base = atomicAdd(&s_cnt, (int)__popcll(b));
            base = __shfl(base, 0);
            if (cnd) {
                int p = base + lane_prefix(b);
                if (p < CAPF) seg[p] = 0.5f * v[i];
            }
        }
    }
    __syncthreads();
    if (tid == 0) { cnts[r] = s_cnt; maxs[r] = s_max; }
}

// ---------------- K2: one wave per row, solve + loss ----------------
__global__ __launch_bounds__(64)
void entmax15_solve(const float* __restrict__ x,
                    const int* __restrict__ tgt,
                    const float* __restrict__ maxs,
                    const int*   __restrict__ cnts,
                    const float* __restrict__ cand,
                    float* __restrict__ partial) {
    const int lane = threadIdx.x;
    const int r    = blockIdx.x;
    const float* row = x + (size_t)r * D;
    const float* seg = cand + (size_t)r * CAPF;

    const int   cnt  = cnts[r];
    const float xmax = maxs[r];
    const bool  ovf  = cnt > CAPF;    // P ~ 7e-13: correctness fallback only
    const int   nn   = ovf ? 0 : cnt;

    const float c    = 0.5f * xmax;
    const float Tcap = c - 0.0055f;   // tau <= c - 1/sqrt(d) always
    float T = c - 1.0f;

    // Newton from below: f(T) = sum u^2 - 1, u = max(y-T,0)
    for (int it = 0; it < NEWTON_IT; ++it) {
        float S1 = 0.f, S2 = 0.f;
        for (int j = lane; j < nn; j += 64) {
            float u = fmaxf(seg[j] - T, 0.f);
            S1 += u; S2 = fmaf(u, u, S2);
        }
        if (ovf)
            for (int j = lane; j < D; j += 64) {
                float u = fmaxf(0.5f * row[j] - T, 0.f);
                S1 += u; S2 = fmaf(u, u, S2);
            }
#pragma unroll
        for (int off = 32; off > 0; off >>= 1) {
            S1 += __shfl_xor(S1, off);
            S2 += __shfl_xor(S2, off);
        }
        T = fminf(T + 0.5f * (S2 - 1.0f) / S1, Tcap);
    }

    // exact quadratic solve over stabilized support (reference formula)
    {
        float k = 0.f, B = 0.f, A = 0.f;
        for (int j = lane; j < nn; j += 64) {
            float y = seg[j];
            if (y > T) { k += 1.f; B += y; A = fmaf(y, y, A); }
        }
        if (ovf)
            for (int j = lane; j < D; j += 64) {
                float y = 0.5f * row[j];
                if (y > T) { k += 1.f; B += y; A = fmaf(y, y, A); }
            }
#pragma unroll
        for (int off = 32; off > 0; off >>= 1) {
            k += __shfl_xor(k, off);
            B += __shfl_xor(B, off);
            A += __shfl_xor(A, off);
        }
        float mean  = B / k;
        float delta = fmaxf(fmaf(mean, mean, -(A - 1.f) / k), 0.f);
        T = fminf(mean - sqrtf(delta), Tcap);
    }

    // loss: S15 = sum u^3, Spx = sum u^2 * 2y  (u = y - T > 0)
    float S15 = 0.f, Spx = 0.f;
    for (int j = lane; j < nn; j += 64) {
        float y = seg[j];
        float u = y - T;
        if (u > 0.f) { float p = u * u; S15 = fmaf(p, u, S15); Spx = fmaf(p, 2.f * y, Spx); }
    }
    if (ovf)
        for (int j = lane; j < D; j += 64) {
            float xv = row[j];
            float u  = 0.5f * xv - T;
            if (u > 0.f) { float p = u * u; S15 = fmaf(p, u, S15); Spx = fmaf(p, xv, Spx); }
        }
#pragma unroll
    for (int off = 32; off > 0; off >>= 1) {
        S15 += __shfl_xor(S15, off);
        Spx += __shfl_xor(Spx, off);
    }

    if (lane == 0) {
        float xt   = row[tgt[r]];
        partial[r] = (1.f - S15) * (4.f / 3.f) + Spx - xt;
    }
}

// ---------------- K3: reduce ----------------
__global__ __launch_bounds__(1024)
void reduce_partials(const float* __restrict__ p, float* __restrict__ out,
                     int n, float inv_n) {
    __shared__ float s_red[16];
    const int tid = threadIdx.x, lane = tid & 63, wave = tid >> 6;
    float v = 0.f;
    for (int i = tid; i < n; i += 1024) v += p[i];
#pragma unroll
    for (int off = 32; off > 0; off >>= 1) v += __shfl_xor(v, off);
    if (lane == 0) s_red[wave] = v;
    __syncthreads();
    if (tid < 64) {
        float t = (lane < 16) ? s_red[lane] : 0.f;
#pragma unroll
        for (int off = 8; off > 0; off >>= 1) t += __shfl_xor(t, off);
        if (lane == 0) out[0] = t * inv_n;
    }
}

// ---------------- fallback: r2 monolithic (ws too small) ----------------
__global__ __launch_bounds__(BLK, 8)
void entmax15_rows(const float* __restrict__ x,
                   const int* __restrict__ tgt,
                   float* __restrict__ out,
                   float inv_n) {
    __shared__ float s_buf[CAPF];
    __shared__ float s_red[16];
    __shared__ float s_max;
    __shared__ int   s_cnt;

    const int tid  = threadIdx.x;
    const int lane = tid & 63;
    const int wave = tid >> 6;
    const int r    = blockIdx.x;
    const float*  row  = x + (size_t)r * D;
    const float4* row4 = (const float4*)row;

    if (tid == 0) s_cnt = 0;

    float v[32];
#pragma unroll
    for (int i = 0; i < 7; ++i) {
        float4 t = row4[tid + i * 1024];
        v[4*i+0] = t.x; v[4*i+1] = t.y; v[4*i+2] = t.z; v[4*i+3] = t.w;
    }
    if (tid < REM4) {
        float4 t = row4[tid + 7 * 1024];
        v[28] = t.x; v[29] = t.y; v[30] = t.z; v[31] = t.w;
    } else {
        v[28] = v[29] = v[30] = v[31] = -1e30f;
    }

    float m = -1e30f;
#pragma unroll
    for (int i = 0; i < 32; ++i) m = fmaxf(m, v[i]);
#pragma unroll
    for (int off = 32; off > 0; off >>= 1) m = fmaxf(m, __shfl_xor(m, off));
    if (lane == 0) s_red[wave] = m;
    __syncthreads();
    if (tid < 64) {
        float mm = (lane < 16) ? s_red[lane] : -1e30f;
#pragma unroll
        for (int off = 8; off > 0; off >>= 1) mm = fmaxf(mm, __shfl_xor(mm, off));
        if (lane == 0) s_max = mm;
    }
    __syncthreads();

    const float xmax = s_max;
    const float thr  = xmax - 2.0f;

#pragma unroll
    for (int i = 0; i < 32; ++i) {
        bool cnd = (v[i] > thr);
        unsigned long long b = __ballot(cnd);
        if (b) {
            int base = 0;
            if (lane == 0) base = atomicAdd(&s_cnt, (int)__popcll(b));
            base = __shfl(base, 0);
            if (cnd) {
                int p = base + lane_prefix(b);
                if (p < CAPF) s_buf[p] = 0.5f * v[i];
            }
        }
    }
    __syncthreads();

    const int  cnt = s_cnt;
    const bool ovf = cnt > CAPF;
    if (tid >= 64) return;

    const float c    = 0.5f * xmax;
    const float Tcap = c - 0.0055f;
    const int   nn   = ovf ? 0 : cnt;
    float T = c - 1.0f;

    for (int it = 0; it < NEWTON_IT; ++it) {
        float S1 = 0.f, S2 = 0.f;
        for (int j = lane; j < nn; j += 64) {
            float u = fmaxf(s_buf[j] - T, 0.f);
            S1 += u; S2 = fmaf(u, u, S2);
        }
        if (ovf)
            for (int j = lane; j < D; j += 64) {
                float u = fmaxf(0.5f * row[j] - T, 0.f);
                S1 += u; S2 = fmaf(u, u, S2);
            }
#pragma unroll
        for (int off = 32; off > 0; off >>= 1) {
            S1 += __shfl_xor(S1, off);
            S2 += __shfl_xor(S2, off);
        }
        T = fminf(T + 0.5f * (S2 - 1.0f) / S1, Tcap);
    }
    {
        float k = 0.f, B = 0.f, A = 0.f;
        for (int j = lane; j < nn; j += 64) {
            float y = s_buf[j];
            if (y > T) { k += 1.f; B += y; A = fmaf(y, y, A); }
        }
        if (ovf)
            for (int j = lane; j < D; j += 64) {
                float y = 0.5f * row[j];
                if (y > T) { k += 1.f; B += y; A = fmaf(y, y, A); }
            }
#pragma unroll
        for (int off = 32; off > 0; off >>= 1) {
            k += __shfl_xor(k, off);
            B += __shfl_xor(B, off);
            A += __shfl_xor(A, off);
        }
        float mean  = B / k;
        float delta = fmaxf(fmaf(mean, mean, -(A - 1.f) / k), 0.f);
        T = fminf(mean - sqrtf(delta), Tcap);
    }
    float S15 = 0.f, Spx = 0.f;
    for (int j = lane; j < nn; j += 64) {
        float y = s_buf[j];
        float u = y - T;
        if (u > 0.f) { float p = u * u; S15 = fmaf(p, u, S15); Spx = fmaf(p, 2.f * y, Spx); }
    }
    if (ovf)
        for (int j = lane; j < D; j += 64) {
            float xv = row[j];
            float u  = 0.5f * xv - T;
            if (u > 0.f) { float p = u * u; S15 = fmaf(p, u, S15); Spx = fmaf(p, xv, Spx); }
        }
#pragma unroll
    for (int off = 32; off > 0; off >>= 1) {
        S15 += __shfl_xor(S15, off);
        Spx += __shfl_xor(Spx, off);
    }
    if (lane == 0) {
        float xt   = row[tgt[r]];
        float loss = (1.f - S15) * (4.f / 3.f) + Spx - xt;
        atomicAdd(out, loss * inv_n);
    }
}

extern "C" void kernel_launch(void* const* d_in, const int* in_sizes, int n_in,
                              void* d_out, int out_size, void* d_ws, size_t ws_size,
                              hipStream_t stream) {
    const float* xin = (const float*)d_in[0];
    const int*   tgt = (const int*)d_in[1];
    float*       out = (float*)d_out;
    const int n = in_sizes[0] / D;           // 4096 rows
    const float inv_n = 1.0f / (float)n;

    // ws layout (floats): [0,n) partial | [n,2n) maxs | [2n,3n) cnts(int)
    //                     | [coff, coff + n*CAPF) candidates
    const size_t coff = ((size_t)3 * n + 63) & ~(size_t)63;
    const size_t need = (coff + (size_t)n * CAPF) * sizeof(float);

    if (d_ws && ws_size >= need) {
        float* wsf     = (float*)d_ws;
        float* partial = wsf;
        float* maxs    = wsf + n;
        int*   cnts    = (int*)(wsf + 2 * (size_t)n);
        float* cand    = wsf + coff;

        entmax15_collect<<<n, BLK, 0, stream>>>(xin, maxs, cnts, cand);
        entmax15_solve<<<n, 64, 0, stream>>>(xin, tgt, maxs, cnts, cand, partial);
        reduce_partials<<<1, 1024, 0, stream>>>(partial, out, n, inv_n);
    } else {
        hipMemsetAsync(out, 0, sizeof(float), stream);
        entmax15_rows<<<n, BLK, 0, stream>>>(xin, tgt, out, inv_n);
    }
}